// Round 7
// baseline (315.726 us; speedup 1.0000x reference)
//
#include <hip/hip_runtime.h>
#include <cstdint>
#include <cstddef>

#define C1 128
#define C2 256
#define Hh 56
#define Wd 56
#define HW 3136                  // 56*56
#define NHW 100352               // 32*3136
#define N1 ((size_t)12845056)    // 32*128*3136
#define N2 ((size_t)25690112)    // 32*256*3136
#define XPSZ ((size_t)13778944)  // 32*58*58*128

typedef int v4i __attribute__((ext_vector_type(4)));
typedef int v16i __attribute__((ext_vector_type(16)));

// ---- workspace layout (bytes) ----
static constexpr size_t OFF_XP = 0;
static constexpr size_t OFF_Q1 = XPSZ;
static constexpr size_t OFF_Q3 = OFF_Q1 + N1;
static constexpr size_t OFF_WQ1 = OFF_Q3 + N2;
static constexpr size_t OFF_WQ2 = OFF_WQ1 + 147456;
static constexpr size_t OFF_STATS = OFF_WQ2 + 32768;

struct Stats {
  int absmax1, absmax2, pad0, pad1;
  float scale1, e1, s2, e2;
  float scaleq2, e3, sf, ef;
  int sum1[C1]; unsigned sumsq1[C1];
  int min1[C1], max1[C1];
  float A1[C1], B1c[C1];
  int sum2[C2]; unsigned sumsq2[C2];
  int min2[C2], max2[C2];
  float A2[C2], B2c[C2];
};

__global__ void k_init(Stats* st) {
  int t = threadIdx.x;
  if (t == 0) { st->absmax1 = 0; st->absmax2 = 0; }
  for (int c = t; c < C1; c += 256) {
    st->sum1[c] = 0; st->sumsq1[c] = 0; st->min1[c] = 127; st->max1[c] = -128;
  }
  for (int c = t; c < C2; c += 256) {
    st->sum2[c] = 0; st->sumsq2[c] = 0; st->min2[c] = 127; st->max2[c] = -128;
  }
}

// x int32 NCHW -> xp int8 [n][hh(58)][k16(8)][ww(58)][16], borders zeroed.
__global__ __launch_bounds__(256) void k_prep_x2(
    const int* __restrict__ x, signed char* __restrict__ xp) {
  __shared__ signed char lds[56 * 132];
  int t = threadIdx.x;
  int hh = blockIdx.x;             // 0..57
  int n = blockIdx.y;
  int* xpw = (int*)(xp + ((size_t)n * 58 + hh) * 7424);
  if (hh == 0 || hh == 57) {
    for (int o = t; o < 1856; o += 256) xpw[o] = 0;
    return;
  }
  int h = hh - 1;
  const int* xb = x + (size_t)n * C1 * HW + h * 56;
  for (int idx = t; idx < 7168; idx += 256) {
    int c = idx / 56, w = idx - c * 56;
    lds[w * 132 + c] = (signed char)xb[(size_t)c * HW + w];
  }
  __syncthreads();
  for (int o = t; o < 1856; o += 256) {
    int kb = o / 232, r = o - kb * 232, ww = r >> 2, cw = r & 3;
    int val = (ww == 0 || ww == 57) ? 0
              : *(const int*)&lds[(ww - 1) * 132 + kb * 16 + cw * 4];
    xpw[o] = val;
  }
}

// wDW [co][ci][3][3] float -> wq1t int8 [k16(72)][co(128)][16], k=pos*128+ci
__global__ void k_prep_w1(const float* __restrict__ wDW, signed char* __restrict__ wq1t) {
  int idx = blockIdx.x * 256 + threadIdx.x;
  if (idx >= 128 * 1152) return;
  int co = idx / 1152, r = idx - co * 1152;
  int ci = r / 9, pos = r - ci * 9;
  int k = pos * 128 + ci;
  wq1t[(size_t)(k >> 4) * 2048 + co * 16 + (k & 15)] = (signed char)(int)wDW[idx];
}

// wPW [co][ci] float -> wq2t int8 [k16(8)][co(256)][16]
__global__ void k_prep_w2(const float* __restrict__ wPW, signed char* __restrict__ wq2t) {
  int i = blockIdx.x * 256 + threadIdx.x;   // 32768
  int co = i >> 7, ci = i & 127;
  wq2t[(size_t)(ci >> 4) * 4096 + co * 16 + (ci & 15)] = (signed char)(int)wPW[i];
}

// exact integer ceil(log2(v)); shift = max(bw-7,0); e_out = ea+eb+shift
__global__ void k_scale(const int* __restrict__ absmax_p,
                        const float* __restrict__ ea, const float* __restrict__ eb,
                        float* scale_out, float* e_out) {
  int v = *absmax_p;
  int p = 31 - __clz(v | 1);
  int bw = ((v & (v - 1)) == 0) ? p : p + 1;
  int shift = bw - 7; if (shift < 0) shift = 0;
  *scale_out = exp2f((float)(-shift));
  *e_out = *ea + *eb + (float)shift;
}

__device__ inline v4i ld16_lds(const signed char* p) {
  const int2* q = (const int2*)p;          // 8-byte aligned
  int2 lo = q[0], hi = q[1];
  v4i r; r[0] = lo.x; r[1] = lo.y; r[2] = hi.x; r[3] = hi.y;
  return r;
}

// 3x3 conv 128->128, block = 256 pixels x 128 co, acc in registers.
// STORE=0: absmax1 only. STORE=1: quantize -> q1 [g][128] + per-channel stats.
template <int STORE>
__global__ __launch_bounds__(256, 2) void k_conv1t(
    const signed char* __restrict__ xp, const signed char* __restrict__ wq1t,
    signed char* __restrict__ q1, Stats* st) {
  __shared__ int qti[256 * 34];            // 256 pixels x 136B
  __shared__ int psum[C1], psq[C1], pmn[C1], pmx[C1];
  __shared__ int reda[4];
  signed char* qt = (signed char*)qti;

  int t = threadIdx.x, lane = t & 63, wave = t >> 6;
  int half = lane >> 5, l31 = lane & 31;
  size_t g0 = (size_t)blockIdx.x * 256;

  const signed char* ab[2];
#pragma unroll
  for (int i = 0; i < 2; ++i) {
    size_t gm = g0 + wave * 64 + i * 32 + l31;
    int n = (int)(gm / HW);
    int p = (int)(gm - (size_t)n * HW);
    int h = p / 56, w = p - h * 56;
    ab[i] = xp + ((size_t)n * 58 + h) * 7424 + w * 16 + half * 928;
  }
  const signed char* bb[4];
#pragma unroll
  for (int j = 0; j < 4; ++j)
    bb[j] = wq1t + (size_t)(j * 32 + l31) * 16 + half * 2048;

  v16i a1[2][4];
#pragma unroll
  for (int i = 0; i < 2; ++i)
#pragma unroll
    for (int j = 0; j < 4; ++j)
#pragma unroll
      for (int r = 0; r < 16; ++r) a1[i][j][r] = 0;

#pragma unroll
  for (int pos = 0; pos < 9; ++pos) {
    int kh = pos / 3, kw = pos - kh * 3;
    const signed char* a0p = ab[0] + kh * 7424 + kw * 16;
    const signed char* a1p = ab[1] + kh * 7424 + kw * 16;
#pragma unroll
    for (int kb = 0; kb < 8; kb += 2) {
      v4i af0 = *(const v4i*)(a0p + kb * 928);
      v4i af1 = *(const v4i*)(a1p + kb * 928);
      v4i bf[4];
#pragma unroll
      for (int j = 0; j < 4; ++j)
        bf[j] = *(const v4i*)(bb[j] + pos * 16384 + kb * 2048);
#pragma unroll
      for (int j = 0; j < 4; ++j) {
        a1[0][j] = __builtin_amdgcn_mfma_i32_32x32x32_i8(af0, bf[j], a1[0][j], 0, 0, 0);
        a1[1][j] = __builtin_amdgcn_mfma_i32_32x32x32_i8(af1, bf[j], a1[1][j], 0, 0, 0);
      }
    }
  }

  if (STORE == 0) {
    int am = 0;
#pragma unroll
    for (int i = 0; i < 2; ++i)
#pragma unroll
      for (int j = 0; j < 4; ++j)
#pragma unroll
        for (int r = 0; r < 16; ++r) am = max(am, abs(a1[i][j][r]));
    for (int off = 32; off; off >>= 1) am = max(am, __shfl_down(am, off, 64));
    if (lane == 0) reda[wave] = am;
    __syncthreads();
    if (t == 0)
      atomicMax(&st->absmax1, max(max(reda[0], reda[1]), max(reda[2], reda[3])));
  } else {
    if (t < C1) { psum[t] = 0; psq[t] = 0; pmn[t] = 127; pmx[t] = -128; }
    __syncthreads();
    float scale1 = st->scale1;
#pragma unroll
    for (int j = 0; j < 4; ++j) {
      int sj = 0, sqj = 0, mnj = 127, mxj = -128;
      int c = j * 32 + l31;
#pragma unroll
      for (int i = 0; i < 2; ++i)
#pragma unroll
        for (int reg = 0; reg < 16; ++reg) {
          int row = (reg & 3) + 8 * (reg >> 2) + 4 * half;
          int pix = wave * 64 + i * 32 + row;
          float r = rintf((float)a1[i][j][reg] * scale1);
          r = fminf(fmaxf(r, -128.f), 127.f);
          int qi = (int)r;
          qt[pix * 136 + c] = (signed char)qi;
          sj += qi; sqj += qi * qi; mnj = min(mnj, qi); mxj = max(mxj, qi);
        }
      sj += __shfl_down(sj, 32, 64);
      sqj += __shfl_down(sqj, 32, 64);
      mnj = min(mnj, __shfl_down(mnj, 32, 64));
      mxj = max(mxj, __shfl_down(mxj, 32, 64));
      if (half == 0) {
        atomicAdd(&psum[c], sj); atomicAdd(&psq[c], sqj);
        atomicMin(&pmn[c], mnj); atomicMax(&pmx[c], mxj);
      }
    }
    __syncthreads();
    if (t < C1) {
      atomicAdd(&st->sum1[t], psum[t]);
      atomicAdd(&st->sumsq1[t], (unsigned)psq[t]);
      atomicMin(&st->min1[t], pmn[t]);
      atomicMax(&st->max1[t], pmx[t]);
    }
    // coalesced LDS -> global copy
    int* q1w = (int*)(q1 + g0 * 128);
    for (int idx = t; idx < 8192; idx += 256) {
      int pix = idx >> 5, c4 = idx & 31;
      q1w[idx] = qti[pix * 34 + c4];
    }
  }
}

// 1x1 conv 128->256. Block = 128 pixels x 256 co; wave = 32 pix x 256 co.
// Rebuilds q2 from q1 via bn1 affine (LDS), MFMA, then (STORE=1) quantize
// into LDS stage and store q3 fully coalesced.
template <int STORE>
__global__ __launch_bounds__(256, 2) void k_conv2t(
    const signed char* __restrict__ q1, const signed char* __restrict__ wq2t,
    signed char* __restrict__ q3, Stats* st) {
  __shared__ int qti[128 * 34];            // 17408 B: q2 tile [128 pix][136]
  __shared__ signed char stg[128 * 264];   // 33792 B: q3 stage [128 pix][264]
  __shared__ int psum[C2], psq[C2], pmn[C2], pmx[C2];
  __shared__ int reda[4];
  signed char* qt = (signed char*)qti;

  int t = threadIdx.x, lane = t & 63, wave = t >> 6;
  int half = lane >> 5, l31 = lane & 31;
  size_t g0 = (size_t)blockIdx.x * 128;

  if (STORE) { psum[t] = 0; psq[t] = 0; pmn[t] = 127; pmx[t] = -128; }

  // bn1 coefficients for this thread's fixed 4 channels
  int c4 = t & 31;
  float Av[4], Bv[4];
#pragma unroll
  for (int jj = 0; jj < 4; ++jj) {
    Av[jj] = st->A1[c4 * 4 + jj];
    Bv[jj] = st->B1c[c4 * 4 + jj];
  }
  float s2 = st->s2;
  const int* q1w = (const int*)(q1 + g0 * 128);
#pragma unroll
  for (int k = 0; k < 16; ++k) {
    int idx = k * 256 + t;
    int v = q1w[idx];
    int pix = idx >> 5;
    int outv = 0;
#pragma unroll
    for (int jj = 0; jj < 4; ++jj) {
      int b = (signed char)(v >> (8 * jj));
      float y = Av[jj] * (float)b + Bv[jj];
      float r = rintf(y * s2);
      r = fminf(fmaxf(r, -128.f), 127.f);
      r = fmaxf(r, 0.f);
      outv |= ((int)r & 0xff) << (8 * jj);
    }
    qti[pix * 34 + c4] = outv;
  }
  __syncthreads();

  v16i acc[8];
#pragma unroll
  for (int j = 0; j < 8; ++j)
#pragma unroll
    for (int r = 0; r < 16; ++r) acc[j][r] = 0;

#pragma unroll
  for (int ks = 0; ks < 4; ++ks) {
    v4i af = ld16_lds(&qt[(wave * 32 + l31) * 136 + half * 16 + ks * 32]);
#pragma unroll
    for (int j = 0; j < 8; ++j) {
      v4i bf = *(const v4i*)(wq2t + (size_t)(ks * 2 + half) * 4096 + (j * 32 + l31) * 16);
      acc[j] = __builtin_amdgcn_mfma_i32_32x32x32_i8(af, bf, acc[j], 0, 0, 0);
    }
  }

  if (STORE == 0) {
    int am2 = 0;
#pragma unroll
    for (int j = 0; j < 8; ++j)
#pragma unroll
      for (int r = 0; r < 16; ++r) am2 = max(am2, abs(acc[j][r]));
    for (int off = 32; off; off >>= 1) am2 = max(am2, __shfl_down(am2, off, 64));
    if (lane == 0) reda[wave] = am2;
    __syncthreads();
    if (t == 0)
      atomicMax(&st->absmax2, max(max(reda[0], reda[1]), max(reda[2], reda[3])));
  } else {
    float scale2 = st->scaleq2;
#pragma unroll
    for (int j = 0; j < 8; ++j) {
      int c = j * 32 + l31;
      int sj = 0, sqj = 0, mnj = 127, mxj = -128;
#pragma unroll
      for (int reg = 0; reg < 16; ++reg) {
        int row = (reg & 3) + 8 * (reg >> 2) + 4 * half;
        float r = rintf((float)acc[j][reg] * scale2);
        r = fminf(fmaxf(r, -128.f), 127.f);
        int qi = (int)r;
        stg[(wave * 32 + row) * 264 + c] = (signed char)qi;
        sj += qi; sqj += qi * qi; mnj = min(mnj, qi); mxj = max(mxj, qi);
      }
      sj += __shfl_down(sj, 32, 64);
      sqj += __shfl_down(sqj, 32, 64);
      mnj = min(mnj, __shfl_down(mnj, 32, 64));
      mxj = max(mxj, __shfl_down(mxj, 32, 64));
      if (half == 0) {
        atomicAdd(&psum[c], sj); atomicAdd(&psq[c], sqj);
        atomicMin(&pmn[c], mnj); atomicMax(&pmx[c], mxj);
      }
    }
    __syncthreads();
    atomicAdd(&st->sum2[t], psum[t]);
    atomicAdd(&st->sumsq2[t], (unsigned)psq[t]);
    atomicMin(&st->min2[t], pmn[t]);
    atomicMax(&st->max2[t], pmx[t]);
    // coalesced stage -> q3 copy: 8192 ints, 256B contiguous per wave-inst
    int* q3w = (int*)(q3 + g0 * 256);
#pragma unroll
    for (int k = 0; k < 32; ++k) {
      int idx = k * 256 + t;
      int pix = idx >> 6, cw = idx & 63;
      q3w[idx] = *(const int*)&stg[pix * 264 + cw * 4];
    }
  }
}

// per-channel bn affine y = A*q + B; global rng from channel min/max extremes.
__global__ void k_bn(const int* __restrict__ sums,
                     const unsigned* __restrict__ sumsqs,
                     const int* __restrict__ mins, const int* __restrict__ maxs,
                     const float* __restrict__ gamma, const float* __restrict__ beta,
                     const float* __restrict__ e_in,
                     float* A, float* Bc, float* s_out, float* e_out,
                     float* e_extra, int C) {
  __shared__ float red[4];
  int t = threadIdx.x;
  float e1 = *e_in;
  double meanq = (double)sums[t] / (double)NHW;
  double varq = (double)sumsqs[t] / (double)NHW - meanq * meanq;
  float se = exp2f(e1);
  float mean = (float)meanq * se;
  float var = (float)varq * se * se;
  float rsq = 1.0f / sqrtf(var + 1e-5f);
  float g = gamma[t], b = beta[t];
  float Avv = g * se * rsq;
  float Bvv = b - g * mean * rsq;
  A[t] = Avv; Bc[t] = Bvv;
  float cand = fmaxf(fabsf(Avv * (float)mins[t] + Bvv), fabsf(Avv * (float)maxs[t] + Bvv));
  for (int off = 32; off; off >>= 1) cand = fmaxf(cand, __shfl_down(cand, off, 64));
  int wave = t >> 6, lane = t & 63;
  if (lane == 0) red[wave] = cand;
  __syncthreads();
  if (t == 0) {
    float rng = red[0];
    for (int i = 1; i < C / 64; i++) rng = fmaxf(rng, red[i]);
    float bwv = ceilf(log2f(rng));
    *s_out = exp2f(7.0f - bwv);
    *e_out = bwv - 7.0f;
    if (e_extra) *e_extra = bwv - 7.0f;
  }
}

// final: q3 [g][256] -> out NCHW float. Writes 256B-coalesced channel rows.
__global__ __launch_bounds__(256) void k_out(
    const signed char* __restrict__ q3, const Stats* __restrict__ st,
    float* __restrict__ out) {
  int t = threadIdx.x, lane = t & 63, wave = t >> 6;
  int nb = blockIdx.x;                 // 1568 = 32n * 49
  int n = nb / 49, p0 = (nb - n * 49) * 64;
  const int* q3w = (const int*)(q3 + ((size_t)n * HW + p0) * 256);
  float sf = st->sf;
  float* ob = out + (size_t)n * C2 * HW + p0 + lane;
#pragma unroll
  for (int i = 0; i < 16; ++i) {
    int cg2 = wave * 16 + i;
    int v = q3w[(size_t)lane * 64 + cg2];
#pragma unroll
    for (int j = 0; j < 4; ++j) {
      int c = cg2 * 4 + j;
      float y = st->A2[c] * (float)((signed char)(v >> (8 * j))) + st->B2c[c];
      float r = rintf(y * sf);
      r = fminf(fmaxf(r, -128.f), 127.f);
      ob[(size_t)c * HW] = fmaxf(r, 0.f);
    }
  }
}

extern "C" void kernel_launch(void* const* d_in, const int* in_sizes, int n_in,
                              void* d_out, int out_size, void* d_ws, size_t ws_size,
                              hipStream_t stream) {
  const int* x = (const int*)d_in[0];
  const float* x_exp = (const float*)d_in[1];
  const float* wDW = (const float*)d_in[2];
  const float* wDW_exp = (const float*)d_in[3];
  const float* wPW = (const float*)d_in[4];
  const float* wPW_exp = (const float*)d_in[5];
  const float* gamma1 = (const float*)d_in[6];
  const float* beta1 = (const float*)d_in[7];
  const float* gamma2 = (const float*)d_in[8];
  const float* beta2 = (const float*)d_in[9];
  float* out = (float*)d_out;

  char* ws = (char*)d_ws;
  signed char* xp2 = (signed char*)(ws + OFF_XP);
  signed char* q1 = (signed char*)(ws + OFF_Q1);
  signed char* q3 = (signed char*)(ws + OFF_Q3);
  signed char* wq1t = (signed char*)(ws + OFF_WQ1);
  signed char* wq2t = (signed char*)(ws + OFF_WQ2);
  Stats* st = (Stats*)(ws + OFF_STATS);

  hipLaunchKernelGGL(k_init, dim3(1), dim3(256), 0, stream, st);
  hipLaunchKernelGGL(k_prep_x2, dim3(58, 32), dim3(256), 0, stream, x, xp2);
  hipLaunchKernelGGL(k_prep_w1, dim3(576), dim3(256), 0, stream, wDW, wq1t);
  hipLaunchKernelGGL(k_prep_w2, dim3(128), dim3(256), 0, stream, wPW, wq2t);

  hipLaunchKernelGGL(k_conv1t<0>, dim3(392), dim3(256), 0, stream,
                     xp2, wq1t, q1, st);
  hipLaunchKernelGGL(k_scale, dim3(1), dim3(1), 0, stream,
                     &st->absmax1, x_exp, wDW_exp, &st->scale1, &st->e1);
  hipLaunchKernelGGL(k_conv1t<1>, dim3(392), dim3(256), 0, stream,
                     xp2, wq1t, q1, st);
  hipLaunchKernelGGL(k_bn, dim3(1), dim3(C1), 0, stream,
                     st->sum1, st->sumsq1, st->min1, st->max1, gamma1, beta1,
                     &st->e1, st->A1, st->B1c, &st->s2, &st->e2, (float*)nullptr, C1);

  hipLaunchKernelGGL(k_conv2t<0>, dim3(784), dim3(256), 0, stream,
                     q1, wq2t, q3, st);
  hipLaunchKernelGGL(k_scale, dim3(1), dim3(1), 0, stream,
                     &st->absmax2, &st->e2, wPW_exp, &st->scaleq2, &st->e3);
  hipLaunchKernelGGL(k_conv2t<1>, dim3(784), dim3(256), 0, stream,
                     q1, wq2t, q3, st);
  hipLaunchKernelGGL(k_bn, dim3(1), dim3(C2), 0, stream,
                     st->sum2, st->sumsq2, st->min2, st->max2, gamma2, beta2,
                     &st->e3, st->A2, st->B2c, &st->sf, &st->ef, out + N2, C2);
  hipLaunchKernelGGL(k_out, dim3(1568), dim3(256), 0, stream, q3, st, out);
}

// Round 8
// 297.733 us; speedup vs baseline: 1.0604x; 1.0604x over previous
//
#include <hip/hip_runtime.h>
#include <cstdint>
#include <cstddef>

#define C1 128
#define C2 256
#define Hh 56
#define Wd 56
#define HW 3136                  // 56*56
#define NHW 100352               // 32*3136
#define N1 ((size_t)12845056)    // 32*128*3136
#define N2 ((size_t)25690112)    // 32*256*3136
#define XPSZ ((size_t)13778944)  // 32*58*58*128

typedef int v4i __attribute__((ext_vector_type(4)));
typedef int v16i __attribute__((ext_vector_type(16)));

// ---- workspace layout (bytes) ----
static constexpr size_t OFF_XP = 0;
static constexpr size_t OFF_ACC1 = XPSZ;                  // int32, 4*N1
static constexpr size_t OFF_Q1 = OFF_ACC1 + 4 * N1;
static constexpr size_t OFF_Q3 = OFF_Q1 + N1;
static constexpr size_t OFF_WQ1 = OFF_Q3 + N2;
static constexpr size_t OFF_WQ2 = OFF_WQ1 + 147456;
static constexpr size_t OFF_STATS = OFF_WQ2 + 32768;

struct Stats {
  int absmax1, absmax2, pad0, pad1;
  float scale1, e1, s2, e2;
  float scaleq2, e3, sf, ef;
  int sum1[C1]; unsigned sumsq1[C1];
  int min1[C1], max1[C1];
  float A1[C1], B1c[C1];
  int sum2[C2]; unsigned sumsq2[C2];
  int min2[C2], max2[C2];
  float A2[C2], B2c[C2];
};

__global__ void k_init(Stats* st) {
  int t = threadIdx.x;
  if (t == 0) { st->absmax1 = 0; st->absmax2 = 0; }
  for (int c = t; c < C1; c += 256) {
    st->sum1[c] = 0; st->sumsq1[c] = 0; st->min1[c] = 127; st->max1[c] = -128;
  }
  for (int c = t; c < C2; c += 256) {
    st->sum2[c] = 0; st->sumsq2[c] = 0; st->min2[c] = 127; st->max2[c] = -128;
  }
}

// x int32 NCHW -> xp int8 [n][hh(58)][k16(8)][ww(58)][16], borders zeroed.
__global__ __launch_bounds__(256) void k_prep_x2(
    const int* __restrict__ x, signed char* __restrict__ xp) {
  __shared__ signed char lds[56 * 132];
  int t = threadIdx.x;
  int hh = blockIdx.x;             // 0..57
  int n = blockIdx.y;
  int* xpw = (int*)(xp + ((size_t)n * 58 + hh) * 7424);
  if (hh == 0 || hh == 57) {
    for (int o = t; o < 1856; o += 256) xpw[o] = 0;
    return;
  }
  int h = hh - 1;
  const int* xb = x + (size_t)n * C1 * HW + h * 56;
  for (int idx = t; idx < 7168; idx += 256) {
    int c = idx / 56, w = idx - c * 56;
    lds[w * 132 + c] = (signed char)xb[(size_t)c * HW + w];
  }
  __syncthreads();
  for (int o = t; o < 1856; o += 256) {
    int kb = o / 232, r = o - kb * 232, ww = r >> 2, cw = r & 3;
    int val = (ww == 0 || ww == 57) ? 0
              : *(const int*)&lds[(ww - 1) * 132 + kb * 16 + cw * 4];
    xpw[o] = val;
  }
}

// wDW [co][ci][3][3] float -> wq1t int8 [k16(72)][co(128)][16], k=pos*128+ci
__global__ void k_prep_w1(const float* __restrict__ wDW, signed char* __restrict__ wq1t) {
  int idx = blockIdx.x * 256 + threadIdx.x;
  if (idx >= 128 * 1152) return;
  int co = idx / 1152, r = idx - co * 1152;
  int ci = r / 9, pos = r - ci * 9;
  int k = pos * 128 + ci;
  wq1t[(size_t)(k >> 4) * 2048 + co * 16 + (k & 15)] = (signed char)(int)wDW[idx];
}

// wPW [co][ci] float -> wq2t int8 [k16(8)][co(256)][16]
__global__ void k_prep_w2(const float* __restrict__ wPW, signed char* __restrict__ wq2t) {
  int i = blockIdx.x * 256 + threadIdx.x;   // 32768
  int co = i >> 7, ci = i & 127;
  wq2t[(size_t)(ci >> 4) * 4096 + co * 16 + (ci & 15)] = (signed char)(int)wPW[i];
}

__device__ inline v4i ld16_lds(const signed char* p) {
  const int2* q = (const int2*)p;          // 8-byte aligned
  int2 lo = q[0], hi = q[1];
  v4i r; r[0] = lo.x; r[1] = lo.y; r[2] = hi.x; r[3] = hi.y;
  return r;
}

// 3x3 conv 128->128, block = 256 pixels x 128 co. Single pass:
// absmax1 + raw acc store in MFMA-register order (all stores 256B coalesced).
__global__ __launch_bounds__(256, 2) void k_conv1s(
    const signed char* __restrict__ xp, const signed char* __restrict__ wq1t,
    int* __restrict__ acc1, Stats* st) {
  __shared__ int reda[4];
  int t = threadIdx.x, lane = t & 63, wave = t >> 6;
  int half = lane >> 5, l31 = lane & 31;
  size_t g0 = (size_t)blockIdx.x * 256;

  const signed char* ab[2];
#pragma unroll
  for (int i = 0; i < 2; ++i) {
    size_t gm = g0 + wave * 64 + i * 32 + l31;
    int n = (int)(gm / HW);
    int p = (int)(gm - (size_t)n * HW);
    int h = p / 56, w = p - h * 56;
    ab[i] = xp + ((size_t)n * 58 + h) * 7424 + w * 16 + half * 928;
  }
  const signed char* bb[4];
#pragma unroll
  for (int j = 0; j < 4; ++j)
    bb[j] = wq1t + (size_t)(j * 32 + l31) * 16 + half * 2048;

  v16i a1[2][4];
#pragma unroll
  for (int i = 0; i < 2; ++i)
#pragma unroll
    for (int j = 0; j < 4; ++j)
#pragma unroll
      for (int r = 0; r < 16; ++r) a1[i][j][r] = 0;

#pragma unroll
  for (int pos = 0; pos < 9; ++pos) {
    int kh = pos / 3, kw = pos - kh * 3;
    const signed char* a0p = ab[0] + kh * 7424 + kw * 16;
    const signed char* a1p = ab[1] + kh * 7424 + kw * 16;
#pragma unroll
    for (int kb = 0; kb < 8; kb += 2) {
      v4i af0 = *(const v4i*)(a0p + kb * 928);
      v4i af1 = *(const v4i*)(a1p + kb * 928);
      v4i bf[4];
#pragma unroll
      for (int j = 0; j < 4; ++j)
        bf[j] = *(const v4i*)(bb[j] + pos * 16384 + kb * 2048);
#pragma unroll
      for (int j = 0; j < 4; ++j) {
        a1[0][j] = __builtin_amdgcn_mfma_i32_32x32x32_i8(af0, bf[j], a1[0][j], 0, 0, 0);
        a1[1][j] = __builtin_amdgcn_mfma_i32_32x32x32_i8(af1, bf[j], a1[1][j], 0, 0, 0);
      }
    }
  }

  int am = 0;
#pragma unroll
  for (int i = 0; i < 2; ++i)
#pragma unroll
    for (int j = 0; j < 4; ++j)
#pragma unroll
      for (int r = 0; r < 16; ++r) am = max(am, abs(a1[i][j][r]));
  for (int off = 32; off; off >>= 1) am = max(am, __shfl_down(am, off, 64));
  if (lane == 0) reda[wave] = am;
  __syncthreads();
  if (t == 0)
    atomicMax(&st->absmax1, max(max(reda[0], reda[1]), max(reda[2], reda[3])));

  // raw-layout coalesced store: 128 x 256B wave-insts
  int* ob = acc1 + (size_t)blockIdx.x * 32768;
#pragma unroll
  for (int i = 0; i < 2; ++i)
#pragma unroll
    for (int j = 0; j < 4; ++j)
#pragma unroll
      for (int reg = 0; reg < 16; ++reg)
        ob[(((wave * 2 + i) * 4 + j) * 16 + reg) * 64 + lane] = a1[i][j][reg];
}

// read acc1 (raw layout, coalesced), quantize -> q1 [g][128] + per-channel stats.
// Computes scale1 inline from absmax1 (exact integer math, bit-identical).
__global__ __launch_bounds__(256, 2) void k_qstats1(
    const int* __restrict__ acc1, signed char* __restrict__ q1, Stats* st,
    const float* __restrict__ x_exp, const float* __restrict__ wDW_exp) {
  __shared__ int qti[256 * 34];            // 256 pixels x 136B
  __shared__ int psum[C1], psq[C1], pmn[C1], pmx[C1];
  signed char* qt = (signed char*)qti;
  int t = threadIdx.x, lane = t & 63, wave = t >> 6;
  int half = lane >> 5, l31 = lane & 31;

  if (t < C1) { psum[t] = 0; psq[t] = 0; pmn[t] = 127; pmx[t] = -128; }
  __syncthreads();

  int v1 = st->absmax1;
  int pw = 31 - __clz(v1 | 1);
  int bw = ((v1 & (v1 - 1)) == 0) ? pw : pw + 1;
  int sh = max(bw - 7, 0);
  float scale1 = exp2f((float)(-sh));
  if (blockIdx.x == 0 && t == 0)
    st->e1 = x_exp[0] + wDW_exp[0] + (float)sh;

  const int* ib = acc1 + (size_t)blockIdx.x * 32768;
#pragma unroll
  for (int j = 0; j < 4; ++j) {
    int sj = 0, sqj = 0, mnj = 127, mxj = -128;
    int c = j * 32 + l31;
#pragma unroll
    for (int i = 0; i < 2; ++i)
#pragma unroll
      for (int reg = 0; reg < 16; ++reg) {
        int av = ib[(((wave * 2 + i) * 4 + j) * 16 + reg) * 64 + lane];
        int row = (reg & 3) + 8 * (reg >> 2) + 4 * half;
        int pix = wave * 64 + i * 32 + row;
        float r = rintf((float)av * scale1);
        r = fminf(fmaxf(r, -128.f), 127.f);
        int qi = (int)r;
        qt[pix * 136 + c] = (signed char)qi;
        sj += qi; sqj += qi * qi; mnj = min(mnj, qi); mxj = max(mxj, qi);
      }
    sj += __shfl_down(sj, 32, 64);
    sqj += __shfl_down(sqj, 32, 64);
    mnj = min(mnj, __shfl_down(mnj, 32, 64));
    mxj = max(mxj, __shfl_down(mxj, 32, 64));
    if (half == 0) {
      atomicAdd(&psum[c], sj); atomicAdd(&psq[c], sqj);
      atomicMin(&pmn[c], mnj); atomicMax(&pmx[c], mxj);
    }
  }
  __syncthreads();
  if (t < C1) {
    atomicAdd(&st->sum1[t], psum[t]);
    atomicAdd(&st->sumsq1[t], (unsigned)psq[t]);
    atomicMin(&st->min1[t], pmn[t]);
    atomicMax(&st->max1[t], pmx[t]);
  }
  int* q1w = (int*)(q1 + (size_t)blockIdx.x * 256 * 128);
  for (int idx = t; idx < 8192; idx += 256) {
    int pix = idx >> 5, c4 = idx & 31;
    q1w[idx] = qti[pix * 34 + c4];
  }
}

// 1x1 conv 128->256. Block = 128 pixels x 256 co; wave = 32 pix x 256 co.
// Rebuilds q2 from q1 via bn1 affine (LDS), MFMA; STORE=0: absmax2,
// STORE=1: quantize (scale inline from absmax2) -> LDS stage -> coalesced q3.
template <int STORE>
__global__ __launch_bounds__(256, 2) void k_conv2t(
    const signed char* __restrict__ q1, const signed char* __restrict__ wq2t,
    signed char* __restrict__ q3, Stats* st, const float* __restrict__ wPW_exp) {
  __shared__ int qti[128 * 34];            // 17408 B
  __shared__ signed char stg[128 * 264];   // 33792 B
  __shared__ int psum[C2], psq[C2], pmn[C2], pmx[C2];
  __shared__ int reda[4];
  signed char* qt = (signed char*)qti;

  int t = threadIdx.x, lane = t & 63, wave = t >> 6;
  int half = lane >> 5, l31 = lane & 31;
  size_t g0 = (size_t)blockIdx.x * 128;

  if (STORE) { psum[t] = 0; psq[t] = 0; pmn[t] = 127; pmx[t] = -128; }

  int c4 = t & 31;
  float Av[4], Bv[4];
#pragma unroll
  for (int jj = 0; jj < 4; ++jj) {
    Av[jj] = st->A1[c4 * 4 + jj];
    Bv[jj] = st->B1c[c4 * 4 + jj];
  }
  float s2 = st->s2;
  const int* q1w = (const int*)(q1 + g0 * 128);
#pragma unroll
  for (int k = 0; k < 16; ++k) {
    int idx = k * 256 + t;
    int v = q1w[idx];
    int pix = idx >> 5;
    int outv = 0;
#pragma unroll
    for (int jj = 0; jj < 4; ++jj) {
      int b = (signed char)(v >> (8 * jj));
      float y = Av[jj] * (float)b + Bv[jj];
      float r = rintf(y * s2);
      r = fminf(fmaxf(r, -128.f), 127.f);
      r = fmaxf(r, 0.f);
      outv |= ((int)r & 0xff) << (8 * jj);
    }
    qti[pix * 34 + c4] = outv;
  }
  __syncthreads();

  v16i acc[8];
#pragma unroll
  for (int j = 0; j < 8; ++j)
#pragma unroll
    for (int r = 0; r < 16; ++r) acc[j][r] = 0;

#pragma unroll
  for (int ks = 0; ks < 4; ++ks) {
    v4i af = ld16_lds(&qt[(wave * 32 + l31) * 136 + half * 16 + ks * 32]);
#pragma unroll
    for (int j = 0; j < 8; ++j) {
      v4i bf = *(const v4i*)(wq2t + (size_t)(ks * 2 + half) * 4096 + (j * 32 + l31) * 16);
      acc[j] = __builtin_amdgcn_mfma_i32_32x32x32_i8(af, bf, acc[j], 0, 0, 0);
    }
  }

  if (STORE == 0) {
    int am2 = 0;
#pragma unroll
    for (int j = 0; j < 8; ++j)
#pragma unroll
      for (int r = 0; r < 16; ++r) am2 = max(am2, abs(acc[j][r]));
    for (int off = 32; off; off >>= 1) am2 = max(am2, __shfl_down(am2, off, 64));
    if (lane == 0) reda[wave] = am2;
    __syncthreads();
    if (t == 0)
      atomicMax(&st->absmax2, max(max(reda[0], reda[1]), max(reda[2], reda[3])));
  } else {
    int v2 = st->absmax2;
    int pw = 31 - __clz(v2 | 1);
    int bw = ((v2 & (v2 - 1)) == 0) ? pw : pw + 1;
    int sh2 = max(bw - 7, 0);
    float scale2 = exp2f((float)(-sh2));
    if (blockIdx.x == 0 && t == 0)
      st->e3 = st->e2 + wPW_exp[0] + (float)sh2;
#pragma unroll
    for (int j = 0; j < 8; ++j) {
      int c = j * 32 + l31;
      int sj = 0, sqj = 0, mnj = 127, mxj = -128;
#pragma unroll
      for (int reg = 0; reg < 16; ++reg) {
        int row = (reg & 3) + 8 * (reg >> 2) + 4 * half;
        float r = rintf((float)acc[j][reg] * scale2);
        r = fminf(fmaxf(r, -128.f), 127.f);
        int qi = (int)r;
        stg[(wave * 32 + row) * 264 + c] = (signed char)qi;
        sj += qi; sqj += qi * qi; mnj = min(mnj, qi); mxj = max(mxj, qi);
      }
      sj += __shfl_down(sj, 32, 64);
      sqj += __shfl_down(sqj, 32, 64);
      mnj = min(mnj, __shfl_down(mnj, 32, 64));
      mxj = max(mxj, __shfl_down(mxj, 32, 64));
      if (half == 0) {
        atomicAdd(&psum[c], sj); atomicAdd(&psq[c], sqj);
        atomicMin(&pmn[c], mnj); atomicMax(&pmx[c], mxj);
      }
    }
    __syncthreads();
    atomicAdd(&st->sum2[t], psum[t]);
    atomicAdd(&st->sumsq2[t], (unsigned)psq[t]);
    atomicMin(&st->min2[t], pmn[t]);
    atomicMax(&st->max2[t], pmx[t]);
    int* q3w = (int*)(q3 + g0 * 256);
#pragma unroll
    for (int k = 0; k < 32; ++k) {
      int idx = k * 256 + t;
      int pix = idx >> 6, cw = idx & 63;
      q3w[idx] = *(const int*)&stg[pix * 264 + cw * 4];
    }
  }
}

// per-channel bn affine y = A*q + B; global rng from channel min/max extremes.
__global__ void k_bn(const int* __restrict__ sums,
                     const unsigned* __restrict__ sumsqs,
                     const int* __restrict__ mins, const int* __restrict__ maxs,
                     const float* __restrict__ gamma, const float* __restrict__ beta,
                     const float* __restrict__ e_in,
                     float* A, float* Bc, float* s_out, float* e_out,
                     float* e_extra, int C) {
  __shared__ float red[4];
  int t = threadIdx.x;
  float e1 = *e_in;
  double meanq = (double)sums[t] / (double)NHW;
  double varq = (double)sumsqs[t] / (double)NHW - meanq * meanq;
  float se = exp2f(e1);
  float mean = (float)meanq * se;
  float var = (float)varq * se * se;
  float rsq = 1.0f / sqrtf(var + 1e-5f);
  float g = gamma[t], b = beta[t];
  float Avv = g * se * rsq;
  float Bvv = b - g * mean * rsq;
  A[t] = Avv; Bc[t] = Bvv;
  float cand = fmaxf(fabsf(Avv * (float)mins[t] + Bvv), fabsf(Avv * (float)maxs[t] + Bvv));
  for (int off = 32; off; off >>= 1) cand = fmaxf(cand, __shfl_down(cand, off, 64));
  int wave = t >> 6, lane = t & 63;
  if (lane == 0) red[wave] = cand;
  __syncthreads();
  if (t == 0) {
    float rng = red[0];
    for (int i = 1; i < C / 64; i++) rng = fmaxf(rng, red[i]);
    float bwv = ceilf(log2f(rng));
    *s_out = exp2f(7.0f - bwv);
    *e_out = bwv - 7.0f;
    if (e_extra) *e_extra = bwv - 7.0f;
  }
}

// final: q3 [g][256] -> out NCHW float via LDS transpose.
// Phase 1: coalesced q3 reads into [64 pix][260] tile. Phase 2: lane=pixel,
// per-channel coalesced 256B float stores. No divergent global access.
__global__ __launch_bounds__(256) void k_out(
    const signed char* __restrict__ q3, const Stats* __restrict__ st,
    float* __restrict__ out) {
  __shared__ signed char lds[64 * 260];
  int t = threadIdx.x, lane = t & 63, wave = t >> 6;
  size_t g0 = (size_t)blockIdx.x * 64;     // 1568 blocks
  int n = (int)(g0 / HW), p0 = (int)(g0 - (size_t)n * HW);
  const int* q3w = (const int*)(q3 + g0 * 256);
#pragma unroll
  for (int k = 0; k < 16; ++k) {
    int idx = k * 256 + t;
    int pix = idx >> 6, cw = idx & 63;
    *(int*)&lds[pix * 260 + cw * 4] = q3w[idx];
  }
  __syncthreads();
  float sf = st->sf;
  float* ob = out + (size_t)n * C2 * HW + p0 + lane;
#pragma unroll
  for (int cg = 0; cg < 16; ++cg) {
    int v = *(const int*)&lds[lane * 260 + wave * 64 + cg * 4];
#pragma unroll
    for (int jj = 0; jj < 4; ++jj) {
      int c = wave * 64 + cg * 4 + jj;
      float y = st->A2[c] * (float)((signed char)(v >> (8 * jj))) + st->B2c[c];
      float r = rintf(y * sf);
      r = fminf(fmaxf(r, -128.f), 127.f);
      ob[(size_t)c * HW] = fmaxf(r, 0.f);
    }
  }
}

extern "C" void kernel_launch(void* const* d_in, const int* in_sizes, int n_in,
                              void* d_out, int out_size, void* d_ws, size_t ws_size,
                              hipStream_t stream) {
  const int* x = (const int*)d_in[0];
  const float* x_exp = (const float*)d_in[1];
  const float* wDW = (const float*)d_in[2];
  const float* wDW_exp = (const float*)d_in[3];
  const float* wPW = (const float*)d_in[4];
  const float* wPW_exp = (const float*)d_in[5];
  const float* gamma1 = (const float*)d_in[6];
  const float* beta1 = (const float*)d_in[7];
  const float* gamma2 = (const float*)d_in[8];
  const float* beta2 = (const float*)d_in[9];
  float* out = (float*)d_out;

  char* ws = (char*)d_ws;
  signed char* xp2 = (signed char*)(ws + OFF_XP);
  int* acc1 = (int*)(ws + OFF_ACC1);
  signed char* q1 = (signed char*)(ws + OFF_Q1);
  signed char* q3 = (signed char*)(ws + OFF_Q3);
  signed char* wq1t = (signed char*)(ws + OFF_WQ1);
  signed char* wq2t = (signed char*)(ws + OFF_WQ2);
  Stats* st = (Stats*)(ws + OFF_STATS);

  hipLaunchKernelGGL(k_init, dim3(1), dim3(256), 0, stream, st);
  hipLaunchKernelGGL(k_prep_x2, dim3(58, 32), dim3(256), 0, stream, x, xp2);
  hipLaunchKernelGGL(k_prep_w1, dim3(576), dim3(256), 0, stream, wDW, wq1t);
  hipLaunchKernelGGL(k_prep_w2, dim3(128), dim3(256), 0, stream, wPW, wq2t);

  hipLaunchKernelGGL(k_conv1s, dim3(392), dim3(256), 0, stream,
                     xp2, wq1t, acc1, st);
  hipLaunchKernelGGL(k_qstats1, dim3(392), dim3(256), 0, stream,
                     acc1, q1, st, x_exp, wDW_exp);
  hipLaunchKernelGGL(k_bn, dim3(1), dim3(C1), 0, stream,
                     st->sum1, st->sumsq1, st->min1, st->max1, gamma1, beta1,
                     &st->e1, st->A1, st->B1c, &st->s2, &st->e2, (float*)nullptr, C1);

  hipLaunchKernelGGL(k_conv2t<0>, dim3(784), dim3(256), 0, stream,
                     q1, wq2t, q3, st, wPW_exp);
  hipLaunchKernelGGL(k_conv2t<1>, dim3(784), dim3(256), 0, stream,
                     q1, wq2t, q3, st, wPW_exp);
  hipLaunchKernelGGL(k_bn, dim3(1), dim3(C2), 0, stream,
                     st->sum2, st->sumsq2, st->min2, st->max2, gamma2, beta2,
                     &st->e3, st->A2, st->B2c, &st->sf, &st->ef, out + N2, C2);
  hipLaunchKernelGGL(k_out, dim3(1568), dim3(256), 0, stream, q3, st, out);
}